// Round 1
// baseline (186.427 us; speedup 1.0000x reference)
//
#include <hip/hip_runtime.h>

#define T_DIM 512
#define B_DIM 128
#define E_DIM 256

typedef __attribute__((ext_vector_type(8))) short bf16x8;
typedef __attribute__((ext_vector_type(4))) float f32x4;
typedef __attribute__((ext_vector_type(8))) unsigned short u16x8;

__device__ __forceinline__ unsigned short f2bf(float f) {
    unsigned int x = __float_as_uint(f);
    unsigned int r = (x + 0x7FFFu + ((x >> 16) & 1u)) >> 16;  // RNE
    return (unsigned short)r;
}

__device__ __forceinline__ void load16_lds(const void* g, void* l) {
    __builtin_amdgcn_global_load_lds(
        (const __attribute__((address_space(1))) unsigned int*)(unsigned long long)g,
        (__attribute__((address_space(3))) unsigned int*)(unsigned int)(unsigned long long)l,
        16, 0, 0);
}

// Kernel 1: per-slot reverse-cumsum chains -> W[b][t][tau] in bf16.
// rc_t[tau] = relu(rc_{t-1}[tau] - u_t) + d_t  (starts at t==tau with d_tau)
// W[t][tau] = min(1, rc_t[tau]) - min(1, rc_t[tau+1])
// Each thread runs chain tau AND chain tau+1 (redundant) -> no cross-lane comm.
__global__ void __launch_bounds__(128) stack_weights(
    const float* __restrict__ u, const float* __restrict__ d,
    unsigned short* __restrict__ W)
{
    const int j   = blockIdx.x;        // tau block 0..3
    const int b   = blockIdx.y;
    const int tid = threadIdx.x;       // 0..127
    const int tau = j * 128 + tid;
    const int t0  = j * 128;           // GEMM only reads t >= 128*floor(tau/128)

    __shared__ float2 ud[T_DIM];
    for (int i = tid; i < T_DIM - t0; i += 128) {
        int t = t0 + i;
        ud[i] = make_float2(u[t * B_DIM + b], d[t * B_DIM + b]);
    }
    __syncthreads();

    float rc0 = 0.f, rc1 = 0.f;
    unsigned short* Wb = W + (size_t)b * T_DIM * T_DIM + tau;
    for (int t = t0; t < T_DIM; ++t) {
        float2 x = ud[t - t0];
        rc0 = (t >= tau)     ? fmaxf(rc0 - x.x, 0.f) + x.y : 0.f;
        rc1 = (t >= tau + 1) ? fmaxf(rc1 - x.x, 0.f) + x.y : 0.f;
        float w = fminf(rc0, 1.f) - fminf(rc1, 1.f);
        Wb[(size_t)t * T_DIM] = f2bf(w);
    }
}

// Kernel 2: v [T,B,E] fp32 -> Vt [B][E][T] bf16 (B^T layout for the GEMM).
__global__ void __launch_bounds__(256) cast_transpose(
    const float* __restrict__ v, unsigned short* __restrict__ Vt)
{
    const int t0  = blockIdx.x * 64;
    const int e0  = blockIdx.y * 64;
    const int b   = blockIdx.z;
    const int tid = threadIdx.x;
    __shared__ unsigned short tile[64][72];   // [e_local][t_local], pad 8

    #pragma unroll
    for (int it = 0; it < 4; ++it) {
        int lin = it * 256 + tid;          // 0..1023
        int tl  = lin >> 4;                // t_local 0..63
        int c4  = (lin & 15) << 2;         // e_local base
        const float4 val = *(const float4*)(v + ((size_t)(t0 + tl) * B_DIM + b) * E_DIM + e0 + c4);
        tile[c4 + 0][tl] = f2bf(val.x);
        tile[c4 + 1][tl] = f2bf(val.y);
        tile[c4 + 2][tl] = f2bf(val.z);
        tile[c4 + 3][tl] = f2bf(val.w);
    }
    __syncthreads();
    #pragma unroll
    for (int it = 0; it < 2; ++it) {
        int lin = it * 256 + tid;          // 0..511
        int er  = lin >> 3;                // e_local 0..63
        int tc  = (lin & 7) << 3;          // t offset 0..56
        u16x8 val = *(const u16x8*)&tile[er][tc];
        *(u16x8*)(Vt + ((size_t)b * E_DIM + e0 + er) * T_DIM + t0 + tc) = val;
    }
}

// Kernel 3: per-b triangular GEMM  out[t,b,:] = sum_tau W[b][t][tau] * Vt[b][:][tau]
// m97 recipe: 128x128 tile, BK=32, mfma_f32_16x16x32_bf16, global_load_lds(16B).
__global__ void __launch_bounds__(256) stack_gemm(
    const unsigned short* __restrict__ W, const unsigned short* __restrict__ Vt,
    float* __restrict__ out)
{
    const int lin  = blockIdx.x;           // 0..1023
    const int trow = 3 - (lin >> 8);       // heavy K first
    const int rest = lin & 255;
    const int ecol = rest >> 7;
    const int b    = rest & 127;

    const int tid  = threadIdx.x;
    const int lane = tid & 63;
    const int wave = tid >> 6;
    const int wr = wave >> 1, wc = wave & 1;
    const int l15 = lane & 15, quad = lane >> 4;

    __shared__ unsigned short As[128 * 32]; // [t_local][k] rows of 64B
    __shared__ unsigned short Bs[128 * 32]; // [e_local][k] rows of 64B (B^T)

    const unsigned short* Ag = W  + (size_t)b * T_DIM * T_DIM + (size_t)(trow * 128) * T_DIM;
    const unsigned short* Bg = Vt + ((size_t)b * E_DIM + ecol * 128) * T_DIM;

    f32x4 acc[4][4];
    #pragma unroll
    for (int i = 0; i < 4; ++i)
        #pragma unroll
        for (int jj = 0; jj < 4; ++jj)
            acc[i][jj] = f32x4{0.f, 0.f, 0.f, 0.f};

    const int Kext = (trow + 1) * 128;
    for (int k0 = 0; k0 < Kext; k0 += 32) {
        #pragma unroll
        for (int c = 0; c < 2; ++c) {
            int chunk = c * 256 + tid;     // 0..511 (16B chunks)
            int r  = chunk >> 2;           // tile row
            int co = (chunk & 3) << 3;     // col offset (bf16 elems)
            load16_lds(Ag + (size_t)r * T_DIM + k0 + co, &As[chunk * 8]);
        }
        #pragma unroll
        for (int c = 0; c < 2; ++c) {
            int chunk = c * 256 + tid;
            int r  = chunk >> 2;
            int co = (chunk & 3) << 3;
            load16_lds(Bg + (size_t)r * T_DIM + k0 + co, &Bs[chunk * 8]);
        }
        __syncthreads();   // compiler emits s_waitcnt vmcnt(0) before barrier

        bf16x8 af[4], bfr[4];
        #pragma unroll
        for (int mt = 0; mt < 4; ++mt)
            af[mt] = *(const bf16x8*)&As[(wr * 64 + mt * 16 + l15) * 32 + quad * 8];
        #pragma unroll
        for (int nt = 0; nt < 4; ++nt)
            bfr[nt] = *(const bf16x8*)&Bs[(wc * 64 + nt * 16 + l15) * 32 + quad * 8];
        #pragma unroll
        for (int mt = 0; mt < 4; ++mt)
            #pragma unroll
            for (int nt = 0; nt < 4; ++nt)
                acc[mt][nt] = __builtin_amdgcn_mfma_f32_16x16x32_bf16(af[mt], bfr[nt], acc[mt][nt], 0, 0, 0);
        __syncthreads();
    }

    // Epilogue: C/D layout col=lane&15, row=quad*4+reg (m89-verified)
    #pragma unroll
    for (int mt = 0; mt < 4; ++mt) {
        #pragma unroll
        for (int nt = 0; nt < 4; ++nt) {
            #pragma unroll
            for (int r = 0; r < 4; ++r) {
                int gt = trow * 128 + wr * 64 + mt * 16 + quad * 4 + r;
                int ge = ecol * 128 + wc * 64 + nt * 16 + l15;
                out[((size_t)gt * B_DIM + b) * E_DIM + ge] = acc[mt][nt][r];
            }
        }
    }
}

extern "C" void kernel_launch(void* const* d_in, const int* in_sizes, int n_in,
                              void* d_out, int out_size, void* d_ws, size_t ws_size,
                              hipStream_t stream) {
    const float* v = (const float*)d_in[0];
    const float* u = (const float*)d_in[1];
    const float* d = (const float*)d_in[2];
    float* out = (float*)d_out;

    unsigned short* W  = (unsigned short*)d_ws;                                    // 64 MiB
    unsigned short* Vt = (unsigned short*)((char*)d_ws + (size_t)B_DIM * T_DIM * T_DIM * 2);  // 32 MiB

    stack_weights<<<dim3(4, B_DIM), 128, 0, stream>>>(u, d, W);
    cast_transpose<<<dim3(T_DIM / 64, E_DIM / 64, B_DIM), 256, 0, stream>>>(v, Vt);
    stack_gemm<<<dim3(1024), 256, 0, stream>>>(W, Vt, out);
}

// Round 2
// 172.053 us; speedup vs baseline: 1.0835x; 1.0835x over previous
//
#include <hip/hip_runtime.h>

#define T_DIM 512
#define B_DIM 128
#define E_DIM 256

// Closed-form stack math (exact max-plus identity, no approximation):
//   rc_t[tau] = S[t] + max_{m in [tau,t]} g[m],  S = incl. prefix sum of (d-u),
//   g[m] = d[m] - S[m].
//   W[t][tau] != 0 only at right-to-left record positions of g (NGL chain from t),
//   truncated once S[t] + g[m] >= 1.  out[t,b,:] = sum of ~3-6 weighted v rows.

struct Node { float g; int ngl; };   // g value + next-greater-to-left index

// Kernel 1: per-b prep. Hillis-Steele scan for S, then per-tau serial NGL
// search (expected distance ~H(512) ≈ 6 LDS reads; worst case 512, still fine).
__global__ void __launch_bounds__(512) scan_prep(
    const float* __restrict__ u, const float* __restrict__ d,
    float* __restrict__ S_out, Node* __restrict__ nodes)
{
    const int b = blockIdx.x;
    const int t = threadIdx.x;
    __shared__ float sbuf[T_DIM];
    __shared__ float gbuf[T_DIM];

    const float dv = d[t * B_DIM + b];
    const float du = dv - u[t * B_DIM + b];

    sbuf[t] = du;
    __syncthreads();
    float x = du;
    for (int off = 1; off < T_DIM; off <<= 1) {
        float y = (t >= off) ? sbuf[t - off] : 0.f;
        __syncthreads();          // all reads done before any write
        x += y;
        sbuf[t] = x;
        __syncthreads();
    }
    const float S = x;            // inclusive prefix sum of (d-u)
    const float g = dv - S;
    gbuf[t] = g;
    __syncthreads();

    int m = t - 1;
    while (m >= 0 && gbuf[m] <= g) --m;   // strict >: ties (popped-to-zero slots) skipped

    S_out[b * T_DIM + t] = S;
    nodes[b * T_DIM + t] = Node{g, m};
}

// Kernel 2: one wave per (t,b). Walk the NGL chain from t, accumulating
//   w_i = min(1, S[t]+g[m_i]) - min(1, S[t]+g[m_{i-1}])   (prev starts at 0)
// times v[m_i, b, :]. Stop when rc >= 1 (deeper weights exactly 0) or chain ends.
// Lane e-mapping: float4 per lane -> 64*4 = 256 = E_DIM, fully coalesced 1KB rows.
__global__ void __launch_bounds__(256) stack_read(
    const float* __restrict__ v, const float* __restrict__ S_in,
    const Node* __restrict__ nodes, float* __restrict__ out)
{
    const int wid  = (blockIdx.x << 2) | (threadIdx.x >> 6);  // 0..65535
    const int lane = threadIdx.x & 63;
    const int b = wid >> 9;       // consecutive blocks share b, ascending t -> L2 reuse of v rows
    const int t = wid & 511;

    const float S = S_in[b * T_DIM + t];
    const Node* __restrict__ nb = nodes + b * T_DIM;

    float4 acc = {0.f, 0.f, 0.f, 0.f};
    float prev = 0.f;
    int m = t;
    while (true) {
        const Node nd = nb[m];                    // 8B, wave-uniform -> one line
        const float rc  = S + nd.g;
        const float cur = fminf(rc, 1.f);
        const float w   = cur - prev;
        const float4 vv = *(const float4*)(v + ((size_t)m * B_DIM + b) * E_DIM + (lane << 2));
        acc.x += w * vv.x; acc.y += w * vv.y;
        acc.z += w * vv.z; acc.w += w * vv.w;
        prev = cur;
        if (rc >= 1.f || nd.ngl < 0) break;
        m = nd.ngl;
    }
    *(float4*)(out + ((size_t)t * B_DIM + b) * E_DIM + (lane << 2)) = acc;
}

extern "C" void kernel_launch(void* const* d_in, const int* in_sizes, int n_in,
                              void* d_out, int out_size, void* d_ws, size_t ws_size,
                              hipStream_t stream) {
    const float* v = (const float*)d_in[0];
    const float* u = (const float*)d_in[1];
    const float* d = (const float*)d_in[2];
    float* out = (float*)d_out;

    float* S    = (float*)d_ws;                                   // 128*512*4 = 256 KB
    Node*  node = (Node*)((char*)d_ws + (size_t)B_DIM * T_DIM * 4); // 512 KB

    scan_prep<<<dim3(B_DIM), 512, 0, stream>>>(u, d, S, node);
    stack_read<<<dim3((T_DIM * B_DIM) / 4), 256, 0, stream>>>(v, S, node, out);
}

// Round 3
// 138.117 us; speedup vs baseline: 1.3498x; 1.2457x over previous
//
#include <hip/hip_runtime.h>

#define T_DIM 512
#define B_DIM 128
#define E_DIM 256
#define NEG_INF (-1e30f)

// Closed-form stack math (exact max-plus identity):
//   rc_t[tau] = S[t] + max_{m in [tau,t]} g[m],  S = incl. prefix sum of (d-u),
//   g[m] = d[m] - S[m].
//   W[t][tau] != 0 only at right-to-left records of g (NGL chain from t),
//   truncated once S[t] + g[m] >= 1.

struct Node { float g; int ngl; };   // g value + next-greater-to-left index

// Kernel 1: per-b prep. Shuffle wave-scan for S; sparse-table (range-max
// binary descend) for NGL: fixed 10 LDS probes per thread, no divergent scans.
__global__ void __launch_bounds__(512) scan_prep(
    const float* __restrict__ u, const float* __restrict__ d,
    float* __restrict__ S_out, Node* __restrict__ nodes)
{
    const int b    = blockIdx.x;
    const int t    = threadIdx.x;
    const int lane = t & 63;
    const int w    = t >> 6;          // 8 waves

    __shared__ float wsum[8];
    __shared__ float wpre[8];
    __shared__ float M[10][T_DIM];    // M[k][i] = max g over [max(0,i-2^k+1), i]

    const float dv = d[t * B_DIM + b];
    float x = dv - u[t * B_DIM + b];

    // wave-level inclusive scan (6 shfl steps)
    #pragma unroll
    for (int off = 1; off < 64; off <<= 1) {
        float y = __shfl_up(x, off, 64);
        if (lane >= off) x += y;
    }
    if (lane == 63) wsum[w] = x;
    __syncthreads();
    if (t < 8) {                       // tiny exclusive scan of 8 wave totals
        float s = 0.f;
        for (int i = 0; i < t; ++i) s += wsum[i];
        wpre[t] = s;
    }
    __syncthreads();
    const float S = x + wpre[w];       // inclusive prefix sum of (d-u)
    const float g = dv - S;

    // build sparse table: 9 levels of doubling window max
    M[0][t] = g;
    __syncthreads();
    #pragma unroll
    for (int k = 1; k < 10; ++k) {
        int h = 1 << (k - 1);
        float left = (t >= h) ? M[k - 1][t - h] : NEG_INF;
        float mk = fmaxf(M[k - 1][t], left);
        __syncthreads();               // level k-1 reads done
        M[k][t] = mk;
        __syncthreads();
    }

    // binary descend: largest m < t with g[m] > g (strict); else -1.
    int m = t - 1;
    #pragma unroll
    for (int k = 9; k >= 0; --k) {
        if (m >= 0 && M[k][m] <= g) m -= (1 << k);
    }
    if (m < 0) m = -1;

    S_out[(b << 9) | t] = S;
    nodes[(b << 9) | t] = Node{g, m};
}

// Kernel 2: TWO chains per wave (2x memory-level parallelism on the
// latency-bound pointer chase). Lane e-mapping: float4/lane -> 256 = E_DIM.
__global__ void __launch_bounds__(256) stack_read(
    const float* __restrict__ v, const float* __restrict__ S_in,
    const Node* __restrict__ nodes, float* __restrict__ out)
{
    const int wid  = (blockIdx.x << 2) | (threadIdx.x >> 6);  // 0..32767
    const int lane = threadIdx.x & 63;
    const int id0  = wid << 1, id1 = id0 | 1;
    const int b0 = id0 >> 9, t0 = id0 & 511;
    const int b1 = id1 >> 9, t1 = id1 & 511;
    const int e4 = lane << 2;

    const float S0 = S_in[id0];
    const float S1 = S_in[id1];
    const Node* __restrict__ nb0 = nodes + (b0 << 9);
    const Node* __restrict__ nb1 = nodes + (b1 << 9);

    float4 acc0 = {0.f,0.f,0.f,0.f}, acc1 = {0.f,0.f,0.f,0.f};
    float prev0 = 0.f, prev1 = 0.f;
    int m0 = t0, m1 = t1;
    bool act0 = true, act1 = true;

    while (act0 || act1) {
        Node nd0, nd1; float4 vv0, vv1;
        if (act0) {
            nd0 = nb0[m0];
            vv0 = *(const float4*)(v + ((size_t)m0 * B_DIM + b0) * E_DIM + e4);
        }
        if (act1) {
            nd1 = nb1[m1];
            vv1 = *(const float4*)(v + ((size_t)m1 * B_DIM + b1) * E_DIM + e4);
        }
        if (act0) {
            float rc = S0 + nd0.g;
            float cur = fminf(rc, 1.f);
            float wt = cur - prev0;
            acc0.x += wt * vv0.x; acc0.y += wt * vv0.y;
            acc0.z += wt * vv0.z; acc0.w += wt * vv0.w;
            prev0 = cur;
            if (rc >= 1.f || nd0.ngl < 0) act0 = false; else m0 = nd0.ngl;
        }
        if (act1) {
            float rc = S1 + nd1.g;
            float cur = fminf(rc, 1.f);
            float wt = cur - prev1;
            acc1.x += wt * vv1.x; acc1.y += wt * vv1.y;
            acc1.z += wt * vv1.z; acc1.w += wt * vv1.w;
            prev1 = cur;
            if (rc >= 1.f || nd1.ngl < 0) act1 = false; else m1 = nd1.ngl;
        }
    }
    *(float4*)(out + ((size_t)t0 * B_DIM + b0) * E_DIM + e4) = acc0;
    *(float4*)(out + ((size_t)t1 * B_DIM + b1) * E_DIM + e4) = acc1;
}

extern "C" void kernel_launch(void* const* d_in, const int* in_sizes, int n_in,
                              void* d_out, int out_size, void* d_ws, size_t ws_size,
                              hipStream_t stream) {
    const float* v = (const float*)d_in[0];
    const float* u = (const float*)d_in[1];
    const float* d = (const float*)d_in[2];
    float* out = (float*)d_out;

    float* S    = (float*)d_ws;                                     // 256 KB
    Node*  node = (Node*)((char*)d_ws + (size_t)B_DIM * T_DIM * 4); // 512 KB

    scan_prep<<<dim3(B_DIM), 512, 0, stream>>>(u, d, S, node);
    stack_read<<<dim3((T_DIM * B_DIM) / 8), 256, 0, stream>>>(v, S, node, out);
}